// Round 3
// baseline (685.342 us; speedup 1.0000x reference)
//
#include <hip/hip_runtime.h>
#include <hip/hip_bf16.h>

#define IN_CH 64
#define HC 128          // HEADS * OUT_CH
#define NHEAD 4
#define NEG 0.2f
#define CAP 128         // max in-degree staged in LDS (Poisson(16) tail; fallback covers rest)

__device__ __forceinline__ float leaky(float v) { return v >= 0.f ? v : NEG * v; }
__device__ __forceinline__ float bf2f(unsigned short u) {
    return __uint_as_float(((unsigned int)u) << 16);
}

// Two nodes per 256-thread block: h[n] = x[n] @ W (bf16 out); a_src/a_dst fp32.
__global__ void __launch_bounds__(256) k_transform(
        const float* __restrict__ x, const float* __restrict__ W,
        const float* __restrict__ att_src, const float* __restrict__ att_dst,
        __hip_bfloat16* __restrict__ h_bf, float* __restrict__ a_src,
        float* __restrict__ a_dst, int N) {
    const int t = threadIdx.x;
    const int half = t >> 7;             // 0/1
    const int tc = t & 127;              // channel
    const int n = blockIdx.x * 2 + half;
    if (n >= N) return;
    __shared__ float xs[2][IN_CH];
    if (tc < IN_CH) xs[half][tc] = x[(size_t)n * IN_CH + tc];
    __syncthreads();
    float acc = 0.f;
#pragma unroll
    for (int k = 0; k < IN_CH; ++k)
        acc = fmaf(xs[half][k], W[k * HC + tc], acc);
    h_bf[(size_t)n * HC + tc] = __float2bfloat16(acc);

    float ps = acc * att_src[tc];
    float pd = acc * att_dst[tc];
#pragma unroll
    for (int off = 16; off > 0; off >>= 1) {
        ps += __shfl_down(ps, off, 32);
        pd += __shfl_down(pd, off, 32);
    }
    if ((tc & 31) == 0) {
        a_src[n * NHEAD + (tc >> 5)] = ps;
        a_dst[n * NHEAD + (tc >> 5)] = pd;
    }
}

// ---------------- CSR build ----------------
__global__ void k_count(const int* __restrict__ dst, int* __restrict__ deg, int E) {
    int e = blockIdx.x * blockDim.x + threadIdx.x;
    if (e < E) atomicAdd(&deg[dst[e]], 1);
}

// Single-block exclusive scan of deg[0..N) -> rowptr/cursor; rowptr[N]=E.
__global__ void __launch_bounds__(1024) k_scan(const int* __restrict__ deg,
                                               int* __restrict__ rowptr,
                                               int* __restrict__ cursor, int N) {
    const int t = threadIdx.x;
    const int C = (N + 1023) / 1024;
    const int lo = t * C, hi = min(lo + C, N);
    int s = 0;
    for (int i = lo; i < hi; ++i) s += deg[i];
    __shared__ int sh[1024];
    sh[t] = s;
    __syncthreads();
    for (int off = 1; off < 1024; off <<= 1) {
        int v = (t >= off) ? sh[t - off] : 0;
        __syncthreads();
        sh[t] += v;
        __syncthreads();
    }
    int run = t ? sh[t - 1] : 0;
    for (int i = lo; i < hi; ++i) {
        int d = deg[i];
        rowptr[i] = run; cursor[i] = run; run += d;
    }
    if (hi == N && lo <= N) rowptr[N] = run;
}

__global__ void k_fill(const int* __restrict__ src, const int* __restrict__ dst,
                       int* __restrict__ cursor, int* __restrict__ srcbuf, int E) {
    int e = blockIdx.x * blockDim.x + threadIdx.x;
    if (e < E) {
        int p = atomicAdd(&cursor[dst[e]], 1);
        srcbuf[p] = src[e];
    }
}

// ---------------- fused per-node kernel: one wave per node ----------------
__global__ void __launch_bounds__(256) k_node(
        const int* __restrict__ rowptr, const int* __restrict__ srcbuf,
        const float* __restrict__ a_src, const float* __restrict__ a_dst,
        const unsigned short* __restrict__ h_bf, const float* __restrict__ bias,
        float* __restrict__ out, int N) {
    const int lane = threadIdx.x & 63;
    const int w = threadIdx.x >> 6;
    int n = blockIdx.x * 4 + w;
    n = min(n, N - 1);                    // keep barriers uniform; dup writes benign
    const int start = rowptr[n];
    const int deg = rowptr[n + 1] - start;
    const int degc = min(deg, CAP);
    const int myh = lane & 3;

    __shared__ float s_ex[4][CAP * NHEAD];
    __shared__ int   s_src[4][CAP];

    const float ad  = a_dst[n * NHEAD + myh];
    const float asf = a_src[n * NHEAD + myh];

    // pass A: gather a_src once into LDS; max of raw a_src (leaky monotone => fold at end)
    float mxas = asf;
    for (int j = lane >> 2; j < degc; j += 16) {
        const int s = srcbuf[start + j];
        const float as = a_src[s * NHEAD + myh];
        s_ex[w][j * NHEAD + myh] = as;
        if (myh == 0) s_src[w][j] = s;
        mxas = fmaxf(mxas, as);
    }
    for (int j = CAP + (lane >> 2); j < deg; j += 16) {   // rare fallback
        const int s = srcbuf[start + j];
        mxas = fmaxf(mxas, a_src[s * NHEAD + myh]);
    }
#pragma unroll
    for (int off = 4; off < 64; off <<= 1) mxas = fmaxf(mxas, __shfl_xor(mxas, off, 64));
    const float m = leaky(mxas + ad);
    __syncthreads();

    // pass B: exp(e - m) into LDS; per-head sum
    float sm = (lane < 4) ? __expf(leaky(asf + ad) - m) : 0.f;
    for (int j = lane >> 2; j < degc; j += 16) {
        const float as = s_ex[w][j * NHEAD + myh];
        const float ex = __expf(leaky(as + ad) - m);
        s_ex[w][j * NHEAD + myh] = ex;
        sm += ex;
    }
    for (int j = CAP + (lane >> 2); j < deg; j += 16) {   // rare fallback
        const int s = srcbuf[start + j];
        sm += __expf(leaky(a_src[s * NHEAD + myh] + ad) - m);
    }
#pragma unroll
    for (int off = 4; off < 64; off <<= 1) sm += __shfl_xor(sm, off, 64);
    const float r = 1.f / (sm + 1e-16f);
    __syncthreads();

    // pass C: lane handles channels {2*lane, 2*lane+1}; head = lane>>4
    const int hh = lane >> 4;
    const float rh  = __shfl(r, hh, 64);
    const float mh  = __shfl(m, hh, 64);
    const float adh = __shfl(ad, hh, 64);

    float acc0 = 0.f, acc1 = 0.f;
    for (int j = 0; j < degc; ++j) {
        const int s = s_src[w][j];
        const float al = s_ex[w][j * NHEAD + hh] * rh;
        const ushort2 hv = *((const ushort2*)(h_bf + (size_t)s * HC) + lane);
        acc0 = fmaf(al, bf2f(hv.x), acc0);
        acc1 = fmaf(al, bf2f(hv.y), acc1);
    }
    for (int j = CAP; j < deg; ++j) {                     // rare fallback
        const int s = srcbuf[start + j];
        const float al = __expf(leaky(a_src[s * NHEAD + hh] + adh) - mh) * rh;
        const ushort2 hv = *((const ushort2*)(h_bf + (size_t)s * HC) + lane);
        acc0 = fmaf(al, bf2f(hv.x), acc0);
        acc1 = fmaf(al, bf2f(hv.y), acc1);
    }
    // self loop
    {
        const float als = __expf(leaky(asf + ad) - m) * r;   // valid per myh
        const float alh = __shfl(als, hh, 64);
        const ushort2 hv = *((const ushort2*)(h_bf + (size_t)n * HC) + lane);
        acc0 = fmaf(alh, bf2f(hv.x), acc0);
        acc1 = fmaf(alh, bf2f(hv.y), acc1);
    }

    // bias + log_softmax over 128 channels
    float v0 = acc0 + bias[2 * lane];
    float v1 = acc1 + bias[2 * lane + 1];
    float mxv = fmaxf(v0, v1);
#pragma unroll
    for (int off = 1; off < 64; off <<= 1) mxv = fmaxf(mxv, __shfl_xor(mxv, off, 64));
    float se = __expf(v0 - mxv) + __expf(v1 - mxv);
#pragma unroll
    for (int off = 1; off < 64; off <<= 1) se += __shfl_xor(se, off, 64);
    const float lse = mxv + __logf(se);
    float2* op = (float2*)(out + (size_t)n * HC) + lane;
    *op = make_float2(v0 - lse, v1 - lse);
}

extern "C" void kernel_launch(void* const* d_in, const int* in_sizes, int n_in,
                              void* d_out, int out_size, void* d_ws, size_t ws_size,
                              hipStream_t stream) {
    const float* x       = (const float*)d_in[0];
    const int*   ei      = (const int*)d_in[1];
    const float* W       = (const float*)d_in[2];
    const float* att_src = (const float*)d_in[3];
    const float* att_dst = (const float*)d_in[4];
    const float* bias    = (const float*)d_in[5];
    float* out = (float*)d_out;

    const int N = in_sizes[0] / IN_CH;     // 100000
    const int E = in_sizes[1] / 2;         // 1600000
    const int* src = ei;
    const int* dst = ei + E;

    char* wsb = (char*)d_ws;
    __hip_bfloat16* h_bf = (__hip_bfloat16*)wsb;    wsb += (size_t)N * HC * 2;
    float* a_src  = (float*)wsb;                    wsb += (size_t)N * NHEAD * 4;
    float* a_dst  = (float*)wsb;                    wsb += (size_t)N * NHEAD * 4;
    int*   rowptr = (int*)wsb;                      wsb += (size_t)(N + 1) * 4;
    int*   cursor = (int*)wsb;                      wsb += (size_t)N * 4;
    int*   deg    = (int*)wsb;                      wsb += (size_t)N * 4;
    int*   srcbuf = (int*)wsb;                      wsb += (size_t)E * 4;

    hipMemsetAsync(deg, 0, (size_t)N * 4, stream);

    k_transform<<<(N + 1) / 2, 256, 0, stream>>>(x, W, att_src, att_dst, h_bf,
                                                 a_src, a_dst, N);
    k_count<<<(E + 255) / 256, 256, 0, stream>>>(dst, deg, E);
    k_scan<<<1, 1024, 0, stream>>>(deg, rowptr, cursor, N);
    k_fill<<<(E + 255) / 256, 256, 0, stream>>>(src, dst, cursor, srcbuf, E);
    k_node<<<(N + 3) / 4, 256, 0, stream>>>(rowptr, srcbuf, a_src, a_dst,
                                            (const unsigned short*)h_bf, bias, out, N);
}

// Round 4
// 472.836 us; speedup vs baseline: 1.4494x; 1.4494x over previous
//
#include <hip/hip_runtime.h>
#include <hip/hip_bf16.h>

#define IN_CH 64
#define HC 128          // HEADS * OUT_CH
#define NHEAD 4
#define NEG 0.2f
#define CAP 128         // max in-degree staged in LDS (Poisson(16) tail; fallback covers rest)
#define SCAN_CHUNK 1024

__device__ __forceinline__ float leaky(float v) { return v >= 0.f ? v : NEG * v; }
__device__ __forceinline__ float bf2f(unsigned short u) {
    return __uint_as_float(((unsigned int)u) << 16);
}

// Two nodes per 256-thread block: h[n] = x[n] @ W (bf16 out); a_src/a_dst fp32.
__global__ void __launch_bounds__(256) k_transform(
        const float* __restrict__ x, const float* __restrict__ W,
        const float* __restrict__ att_src, const float* __restrict__ att_dst,
        __hip_bfloat16* __restrict__ h_bf, float* __restrict__ a_src,
        float* __restrict__ a_dst, int N) {
    const int t = threadIdx.x;
    const int half = t >> 7;             // 0/1
    const int tc = t & 127;              // channel
    const int n = blockIdx.x * 2 + half;
    if (n >= N) return;
    __shared__ float xs[2][IN_CH];
    if (tc < IN_CH) xs[half][tc] = x[(size_t)n * IN_CH + tc];
    __syncthreads();
    float acc = 0.f;
#pragma unroll
    for (int k = 0; k < IN_CH; ++k)
        acc = fmaf(xs[half][k], W[k * HC + tc], acc);
    h_bf[(size_t)n * HC + tc] = __float2bfloat16(acc);

    float ps = acc * att_src[tc];
    float pd = acc * att_dst[tc];
#pragma unroll
    for (int off = 16; off > 0; off >>= 1) {
        ps += __shfl_down(ps, off, 32);
        pd += __shfl_down(pd, off, 32);
    }
    if ((tc & 31) == 0) {
        a_src[n * NHEAD + (tc >> 5)] = ps;
        a_dst[n * NHEAD + (tc >> 5)] = pd;
    }
}

// ---------------- CSR build ----------------
__global__ void k_count(const int* __restrict__ dst, int* __restrict__ deg, int E) {
    int e = blockIdx.x * blockDim.x + threadIdx.x;
    if (e < E) atomicAdd(&deg[dst[e]], 1);
}

// per-chunk sums (chunk = 1024 elems, 256 threads x 4)
__global__ void __launch_bounds__(256) k_chunk_sum(const int* __restrict__ deg,
                                                   int* __restrict__ bsum, int N) {
    const int t = threadIdx.x;
    int base = blockIdx.x * SCAN_CHUNK + t * 4;
    int s = 0;
#pragma unroll
    for (int k = 0; k < 4; ++k) s += (base + k < N) ? deg[base + k] : 0;
    __shared__ int sh[256];
    sh[t] = s; __syncthreads();
    for (int off = 128; off > 0; off >>= 1) {
        if (t < off) sh[t] += sh[t + off];
        __syncthreads();
    }
    if (t == 0) bsum[blockIdx.x] = sh[0];
}

// parallel exclusive scan of the (<=256) chunk sums; also writes rowptr[N] = E
__global__ void __launch_bounds__(256) k_mid_scan(const int* __restrict__ bsum,
                                                  int* __restrict__ bscan,
                                                  int* __restrict__ rowptr,
                                                  int NB, int N, int E) {
    const int t = threadIdx.x;
    __shared__ int sh[256];
    int v = (t < NB) ? bsum[t] : 0;
    sh[t] = v;
    __syncthreads();
    for (int off = 1; off < 256; off <<= 1) {
        int add = (t >= off) ? sh[t - off] : 0;
        __syncthreads();
        sh[t] += add;
        __syncthreads();
    }
    if (t < NB) bscan[t] = sh[t] - v;   // exclusive
    if (t == 0) rowptr[N] = E;
}

// local exclusive scan per chunk + chunk offset -> rowptr & cursor
__global__ void __launch_bounds__(256) k_scan_final(const int* __restrict__ deg,
                                                    const int* __restrict__ bscan,
                                                    int* __restrict__ rowptr,
                                                    int* __restrict__ cursor, int N) {
    const int t = threadIdx.x;
    int base = blockIdx.x * SCAN_CHUNK + t * 4;
    int v[4]; int tsum = 0;
#pragma unroll
    for (int k = 0; k < 4; ++k) { v[k] = (base + k < N) ? deg[base + k] : 0; tsum += v[k]; }
    __shared__ int sh[256];
    sh[t] = tsum; __syncthreads();
    for (int off = 1; off < 256; off <<= 1) {
        int add = (t >= off) ? sh[t - off] : 0;
        __syncthreads();
        sh[t] += add;
        __syncthreads();
    }
    int run = sh[t] - tsum + bscan[blockIdx.x];
#pragma unroll
    for (int k = 0; k < 4; ++k) {
        if (base + k < N) { rowptr[base + k] = run; cursor[base + k] = run; run += v[k]; }
    }
}

__global__ void k_fill(const int* __restrict__ src, const int* __restrict__ dst,
                       int* __restrict__ cursor, int* __restrict__ srcbuf, int E) {
    int e = blockIdx.x * blockDim.x + threadIdx.x;
    if (e < E) {
        int p = atomicAdd(&cursor[dst[e]], 1);
        srcbuf[p] = src[e];
    }
}

// ---------------- fused per-node kernel: one wave per node ----------------
__global__ void __launch_bounds__(256) k_node(
        const int* __restrict__ rowptr, const int* __restrict__ srcbuf,
        const float* __restrict__ a_src, const float* __restrict__ a_dst,
        const unsigned short* __restrict__ h_bf, const float* __restrict__ bias,
        float* __restrict__ out, int N) {
    const int lane = threadIdx.x & 63;
    const int w = threadIdx.x >> 6;
    int n = blockIdx.x * 4 + w;
    n = min(n, N - 1);                    // keep barriers uniform; dup writes benign
    const int start = rowptr[n];
    const int deg = rowptr[n + 1] - start;
    const int degc = min(deg, CAP);
    const int myh = lane & 3;

    __shared__ float s_ex[4][CAP * NHEAD];
    __shared__ int   s_src[4][CAP];

    const float ad  = a_dst[n * NHEAD + myh];
    const float asf = a_src[n * NHEAD + myh];

    // pass A: gather a_src once into LDS; max of raw a_src (leaky monotone => fold at end)
    float mxas = asf;
    for (int j = lane >> 2; j < degc; j += 16) {
        const int s = srcbuf[start + j];
        const float as = a_src[s * NHEAD + myh];
        s_ex[w][j * NHEAD + myh] = as;
        if (myh == 0) s_src[w][j] = s;
        mxas = fmaxf(mxas, as);
    }
    for (int j = CAP + (lane >> 2); j < deg; j += 16) {   // rare fallback
        const int s = srcbuf[start + j];
        mxas = fmaxf(mxas, a_src[s * NHEAD + myh]);
    }
#pragma unroll
    for (int off = 4; off < 64; off <<= 1) mxas = fmaxf(mxas, __shfl_xor(mxas, off, 64));
    const float m = leaky(mxas + ad);
    __syncthreads();

    // pass B: exp(e - m) into LDS; per-head sum
    float sm = (lane < 4) ? __expf(leaky(asf + ad) - m) : 0.f;
    for (int j = lane >> 2; j < degc; j += 16) {
        const float as = s_ex[w][j * NHEAD + myh];
        const float ex = __expf(leaky(as + ad) - m);
        s_ex[w][j * NHEAD + myh] = ex;
        sm += ex;
    }
    for (int j = CAP + (lane >> 2); j < deg; j += 16) {   // rare fallback
        const int s = srcbuf[start + j];
        sm += __expf(leaky(a_src[s * NHEAD + myh] + ad) - m);
    }
#pragma unroll
    for (int off = 4; off < 64; off <<= 1) sm += __shfl_xor(sm, off, 64);
    const float r = 1.f / (sm + 1e-16f);
    __syncthreads();

    // pass C: lane handles channels {2*lane, 2*lane+1}; head = lane>>4
    const int hh = lane >> 4;
    const float rh  = __shfl(r, hh, 64);
    const float mh  = __shfl(m, hh, 64);
    const float adh = __shfl(ad, hh, 64);

    float acc0 = 0.f, acc1 = 0.f;
    for (int j = 0; j < degc; ++j) {
        const int s = s_src[w][j];
        const float al = s_ex[w][j * NHEAD + hh] * rh;
        const ushort2 hv = *((const ushort2*)(h_bf + (size_t)s * HC) + lane);
        acc0 = fmaf(al, bf2f(hv.x), acc0);
        acc1 = fmaf(al, bf2f(hv.y), acc1);
    }
    for (int j = CAP; j < deg; ++j) {                     // rare fallback
        const int s = srcbuf[start + j];
        const float al = __expf(leaky(a_src[s * NHEAD + hh] + adh) - mh) * rh;
        const ushort2 hv = *((const ushort2*)(h_bf + (size_t)s * HC) + lane);
        acc0 = fmaf(al, bf2f(hv.x), acc0);
        acc1 = fmaf(al, bf2f(hv.y), acc1);
    }
    // self loop
    {
        const float als = __expf(leaky(asf + ad) - m) * r;   // valid per myh
        const float alh = __shfl(als, hh, 64);
        const ushort2 hv = *((const ushort2*)(h_bf + (size_t)n * HC) + lane);
        acc0 = fmaf(alh, bf2f(hv.x), acc0);
        acc1 = fmaf(alh, bf2f(hv.y), acc1);
    }

    // bias + log_softmax over 128 channels
    float v0 = acc0 + bias[2 * lane];
    float v1 = acc1 + bias[2 * lane + 1];
    float mxv = fmaxf(v0, v1);
#pragma unroll
    for (int off = 1; off < 64; off <<= 1) mxv = fmaxf(mxv, __shfl_xor(mxv, off, 64));
    float se = __expf(v0 - mxv) + __expf(v1 - mxv);
#pragma unroll
    for (int off = 1; off < 64; off <<= 1) se += __shfl_xor(se, off, 64);
    const float lse = mxv + __logf(se);
    float2* op = (float2*)(out + (size_t)n * HC) + lane;
    *op = make_float2(v0 - lse, v1 - lse);
}

extern "C" void kernel_launch(void* const* d_in, const int* in_sizes, int n_in,
                              void* d_out, int out_size, void* d_ws, size_t ws_size,
                              hipStream_t stream) {
    const float* x       = (const float*)d_in[0];
    const int*   ei      = (const int*)d_in[1];
    const float* W       = (const float*)d_in[2];
    const float* att_src = (const float*)d_in[3];
    const float* att_dst = (const float*)d_in[4];
    const float* bias    = (const float*)d_in[5];
    float* out = (float*)d_out;

    const int N = in_sizes[0] / IN_CH;     // 100000
    const int E = in_sizes[1] / 2;         // 1600000
    const int* src = ei;
    const int* dst = ei + E;
    const int NB = (N + SCAN_CHUNK - 1) / SCAN_CHUNK;   // 98 (<=256 supported)

    char* wsb = (char*)d_ws;
    __hip_bfloat16* h_bf = (__hip_bfloat16*)wsb;    wsb += (size_t)N * HC * 2;
    float* a_src  = (float*)wsb;                    wsb += (size_t)N * NHEAD * 4;
    float* a_dst  = (float*)wsb;                    wsb += (size_t)N * NHEAD * 4;
    int*   rowptr = (int*)wsb;                      wsb += (size_t)(N + 1) * 4;
    int*   cursor = (int*)wsb;                      wsb += (size_t)N * 4;
    int*   deg    = (int*)wsb;                      wsb += (size_t)N * 4;
    int*   srcbuf = (int*)wsb;                      wsb += (size_t)E * 4;
    int*   bsum   = (int*)wsb;                      wsb += (size_t)NB * 4;
    int*   bscan  = (int*)wsb;                      wsb += (size_t)NB * 4;

    hipMemsetAsync(deg, 0, (size_t)N * 4, stream);

    k_transform<<<(N + 1) / 2, 256, 0, stream>>>(x, W, att_src, att_dst, h_bf,
                                                 a_src, a_dst, N);
    k_count<<<(E + 255) / 256, 256, 0, stream>>>(dst, deg, E);
    k_chunk_sum<<<NB, 256, 0, stream>>>(deg, bsum, N);
    k_mid_scan<<<1, 256, 0, stream>>>(bsum, bscan, rowptr, NB, N, E);
    k_scan_final<<<NB, 256, 0, stream>>>(deg, bscan, rowptr, cursor, N);
    k_fill<<<(E + 255) / 256, 256, 0, stream>>>(src, dst, cursor, srcbuf, E);
    k_node<<<(N + 3) / 4, 256, 0, stream>>>(rowptr, srcbuf, a_src, a_dst,
                                            (const unsigned short*)h_bf, bias, out, N);
}

// Round 5
// 412.244 us; speedup vs baseline: 1.6625x; 1.1470x over previous
//
#include <hip/hip_runtime.h>
#include <hip/hip_bf16.h>

#define IN_CH 64
#define HC 128          // HEADS * OUT_CH
#define NHEAD 4
#define NEG 0.2f
#define CAPB 64         // bucket capacity per node (Poisson(16) max-deg ~45; overflow list covers rest)
#define OF_MAX 65536    // overflow capacity (structurally safe guard)

__device__ __forceinline__ float leaky(float v) { return v >= 0.f ? v : NEG * v; }
__device__ __forceinline__ float bf2f(unsigned short u) {
    return __uint_as_float(((unsigned int)u) << 16);
}

// Two nodes per 256-thread block: h[n] = x[n] @ W (bf16 out); a_src/a_dst fp32.
__global__ void __launch_bounds__(256) k_transform(
        const float* __restrict__ x, const float* __restrict__ W,
        const float* __restrict__ att_src, const float* __restrict__ att_dst,
        __hip_bfloat16* __restrict__ h_bf, float* __restrict__ a_src,
        float* __restrict__ a_dst, int N) {
    const int t = threadIdx.x;
    const int half = t >> 7;             // 0/1
    const int tc = t & 127;              // channel
    const int n = blockIdx.x * 2 + half;
    if (n >= N) return;
    __shared__ float xs[2][IN_CH];
    if (tc < IN_CH) xs[half][tc] = x[(size_t)n * IN_CH + tc];
    __syncthreads();
    float acc = 0.f;
#pragma unroll
    for (int k = 0; k < IN_CH; ++k)
        acc = fmaf(xs[half][k], W[k * HC + tc], acc);
    h_bf[(size_t)n * HC + tc] = __float2bfloat16(acc);

    float ps = acc * att_src[tc];
    float pd = acc * att_dst[tc];
#pragma unroll
    for (int off = 16; off > 0; off >>= 1) {
        ps += __shfl_down(ps, off, 32);
        pd += __shfl_down(pd, off, 32);
    }
    if ((tc & 31) == 0) {
        a_src[n * NHEAD + (tc >> 5)] = ps;
        a_dst[n * NHEAD + (tc >> 5)] = pd;
    }
}

// Fixed-capacity bucket fill: one kernel replaces count+scan+fill.
// cnt is padded: counter for node d lives at cnt[d*16] (one cacheline each).
__global__ void __launch_bounds__(256) k_bucket(
        const int* __restrict__ src, const int* __restrict__ dst,
        int* __restrict__ cnt, int* __restrict__ srcbuf,
        int* __restrict__ oflow, int* __restrict__ oflow_cnt, int E) {
    const int base = (blockIdx.x * blockDim.x + threadIdx.x) * 4;
    if (base + 3 < E) {
        const int4 s4 = *(const int4*)(src + base);
        const int4 d4 = *(const int4*)(dst + base);
        const int ss[4] = {s4.x, s4.y, s4.z, s4.w};
        const int dd[4] = {d4.x, d4.y, d4.z, d4.w};
#pragma unroll
        for (int k = 0; k < 4; ++k) {
            const int p = atomicAdd(&cnt[dd[k] * 16], 1);
            if (p < CAPB) srcbuf[(size_t)dd[k] * CAPB + p] = ss[k];
            else {
                const int q = atomicAdd(oflow_cnt, 1);
                if (q < OF_MAX) { oflow[2 * q] = dd[k]; oflow[2 * q + 1] = ss[k]; }
            }
        }
    } else {
        for (int e = base; e < E; ++e) {
            const int s = src[e], d = dst[e];
            const int p = atomicAdd(&cnt[d * 16], 1);
            if (p < CAPB) srcbuf[(size_t)d * CAPB + p] = s;
            else {
                const int q = atomicAdd(oflow_cnt, 1);
                if (q < OF_MAX) { oflow[2 * q] = d; oflow[2 * q + 1] = s; }
            }
        }
    }
}

// ---------------- fused per-node kernel: one wave per node ----------------
__global__ void __launch_bounds__(256) k_node(
        const int* __restrict__ cnt, const int* __restrict__ srcbuf,
        const int* __restrict__ oflow, const int* __restrict__ oflow_cnt,
        const float* __restrict__ a_src, const float* __restrict__ a_dst,
        const unsigned short* __restrict__ h_bf, const float* __restrict__ bias,
        float* __restrict__ out, int N) {
    const int lane = threadIdx.x & 63;
    const int w = threadIdx.x >> 6;
    int n = blockIdx.x * 4 + w;
    n = min(n, N - 1);                    // keep barriers uniform; dup writes benign
    const size_t start = (size_t)n * CAPB;
    const int deg = min(cnt[n * 16], CAPB);
    const int oc = min(*oflow_cnt, OF_MAX);   // wave-uniform; 0 in practice
    const int myh = lane & 3;

    __shared__ float s_ex[4][CAPB * NHEAD];
    __shared__ int   s_src[4][CAPB];

    const float ad  = a_dst[n * NHEAD + myh];
    const float asf = a_src[n * NHEAD + myh];

    // pass A: gather a_src once into LDS; max of raw a_src (leaky monotone => fold at end)
    float mxas = asf;
    for (int j = lane >> 2; j < deg; j += 16) {
        const int s = srcbuf[start + j];
        const float as = a_src[s * NHEAD + myh];
        s_ex[w][j * NHEAD + myh] = as;
        if (myh == 0) s_src[w][j] = s;
        mxas = fmaxf(mxas, as);
    }
    for (int j = lane >> 2; j < oc; j += 16) {            // overflow (normally empty)
        if (oflow[2 * j] == n)
            mxas = fmaxf(mxas, a_src[oflow[2 * j + 1] * NHEAD + myh]);
    }
#pragma unroll
    for (int off = 4; off < 64; off <<= 1) mxas = fmaxf(mxas, __shfl_xor(mxas, off, 64));
    const float m = leaky(mxas + ad);
    __syncthreads();

    // pass B: exp(e - m) into LDS; per-head sum
    float sm = (lane < 4) ? __expf(leaky(asf + ad) - m) : 0.f;
    for (int j = lane >> 2; j < deg; j += 16) {
        const float as = s_ex[w][j * NHEAD + myh];
        const float ex = __expf(leaky(as + ad) - m);
        s_ex[w][j * NHEAD + myh] = ex;
        sm += ex;
    }
    for (int j = lane >> 2; j < oc; j += 16) {            // overflow (normally empty)
        if (oflow[2 * j] == n)
            sm += __expf(leaky(a_src[oflow[2 * j + 1] * NHEAD + myh] + ad) - m);
    }
#pragma unroll
    for (int off = 4; off < 64; off <<= 1) sm += __shfl_xor(sm, off, 64);
    const float r = 1.f / (sm + 1e-16f);
    __syncthreads();

    // pass C: lane handles channels {2*lane, 2*lane+1}; head = lane>>4
    const int hh = lane >> 4;
    const float rh  = __shfl(r, hh, 64);
    const float mh  = __shfl(m, hh, 64);
    const float adh = __shfl(ad, hh, 64);

    float acc0 = 0.f, acc1 = 0.f;
    for (int j = 0; j < deg; ++j) {
        const int s = s_src[w][j];
        const float al = s_ex[w][j * NHEAD + hh] * rh;
        const ushort2 hv = *((const ushort2*)(h_bf + (size_t)s * HC) + lane);
        acc0 = fmaf(al, bf2f(hv.x), acc0);
        acc1 = fmaf(al, bf2f(hv.y), acc1);
    }
    for (int j = 0; j < oc; ++j) {                        // overflow (normally empty)
        if (oflow[2 * j] == n) {
            const int s = oflow[2 * j + 1];
            const float al = __expf(leaky(a_src[s * NHEAD + hh] + adh) - mh) * rh;
            const ushort2 hv = *((const ushort2*)(h_bf + (size_t)s * HC) + lane);
            acc0 = fmaf(al, bf2f(hv.x), acc0);
            acc1 = fmaf(al, bf2f(hv.y), acc1);
        }
    }
    // self loop
    {
        const float als = __expf(leaky(asf + ad) - m) * r;   // valid per myh
        const float alh = __shfl(als, hh, 64);
        const ushort2 hv = *((const ushort2*)(h_bf + (size_t)n * HC) + lane);
        acc0 = fmaf(alh, bf2f(hv.x), acc0);
        acc1 = fmaf(alh, bf2f(hv.y), acc1);
    }

    // bias + log_softmax over 128 channels
    float v0 = acc0 + bias[2 * lane];
    float v1 = acc1 + bias[2 * lane + 1];
    float mxv = fmaxf(v0, v1);
#pragma unroll
    for (int off = 1; off < 64; off <<= 1) mxv = fmaxf(mxv, __shfl_xor(mxv, off, 64));
    float se = __expf(v0 - mxv) + __expf(v1 - mxv);
#pragma unroll
    for (int off = 1; off < 64; off <<= 1) se += __shfl_xor(se, off, 64);
    const float lse = mxv + __logf(se);
    float2* op = (float2*)(out + (size_t)n * HC) + lane;
    *op = make_float2(v0 - lse, v1 - lse);
}

extern "C" void kernel_launch(void* const* d_in, const int* in_sizes, int n_in,
                              void* d_out, int out_size, void* d_ws, size_t ws_size,
                              hipStream_t stream) {
    const float* x       = (const float*)d_in[0];
    const int*   ei      = (const int*)d_in[1];
    const float* W       = (const float*)d_in[2];
    const float* att_src = (const float*)d_in[3];
    const float* att_dst = (const float*)d_in[4];
    const float* bias    = (const float*)d_in[5];
    float* out = (float*)d_out;

    const int N = in_sizes[0] / IN_CH;     // 100000
    const int E = in_sizes[1] / 2;         // 1600000
    const int* src = ei;
    const int* dst = ei + E;

    char* wsb = (char*)d_ws;
    __hip_bfloat16* h_bf = (__hip_bfloat16*)wsb;    wsb += (size_t)N * HC * 2;      // 25.6 MB
    float* a_src  = (float*)wsb;                    wsb += (size_t)N * NHEAD * 4;   // 1.6 MB
    float* a_dst  = (float*)wsb;                    wsb += (size_t)N * NHEAD * 4;   // 1.6 MB
    int*   cnt    = (int*)wsb;                      wsb += (size_t)N * 16 * 4;      // 6.4 MB (padded)
    int*   oflow_cnt = (int*)wsb;                   wsb += 16 * 4;                  // padded
    int*   oflow  = (int*)wsb;                      wsb += (size_t)OF_MAX * 2 * 4;  // 0.5 MB
    int*   srcbuf = (int*)wsb;                      wsb += (size_t)N * CAPB * 4;    // 25.6 MB

    // zero cnt + oflow_cnt in one shot (adjacent)
    hipMemsetAsync(cnt, 0, ((size_t)N * 16 + 16) * 4, stream);

    k_transform<<<(N + 1) / 2, 256, 0, stream>>>(x, W, att_src, att_dst, h_bf,
                                                 a_src, a_dst, N);
    k_bucket<<<(E / 4 + 255) / 256, 256, 0, stream>>>(src, dst, cnt, srcbuf,
                                                      oflow, oflow_cnt, E);
    k_node<<<(N + 3) / 4, 256, 0, stream>>>(cnt, srcbuf, oflow, oflow_cnt,
                                            a_src, a_dst,
                                            (const unsigned short*)h_bf, bias, out, N);
}